// Round 2
// baseline (241.147 us; speedup 1.0000x reference)
//
#include <hip/hip_runtime.h>

#define TOKS   32768
#define NEXP   64
#define DDIM   1024
#define SEQ    8192
#define NBATCH 4
#define TPB    64      // tokens per block
#define STR    68      // epilogue row stride (floats)
#define CSTR   21      // candidate row stride
#define BK     64      // K-chunk
#define NCHK   (DDIM / BK)          // 16
#define WTILE  (NEXP * 16 * 16)     // 16384 B per chunk: 64 rows x 16 slots x 16B

typedef __attribute__((ext_vector_type(8)))  short short8v;  // 8 bf16 (4 VGPR) MFMA operand
typedef __attribute__((ext_vector_type(16))) float f32x16;   // 32x32 accumulator

// exact RNE float->bf16 (branchless), and exact bf16->float
__device__ __forceinline__ unsigned f2bf(float x) {
  unsigned u = __float_as_uint(x);
  return (u + 0x7fffu + ((u >> 16) & 1u)) >> 16;
}
__device__ __forceinline__ float bf2f(unsigned h) { return __uint_as_float(h << 16); }

__device__ __forceinline__ void gload_lds16(const void* g, void* s) {
  __builtin_amdgcn_global_load_lds(
      (const __attribute__((address_space(1))) unsigned int*)g,
      (__attribute__((address_space(3))) unsigned int*)s, 16, 0, 0);
}

// convert 8 consecutive-k floats -> packed bf16 hi (4 u32) and lo (4 u32)
__device__ __forceinline__ void conv8(const float4 p0, const float4 p1,
                                      unsigned* h, unsigned* lo) {
  float ff[8] = {p0.x, p0.y, p0.z, p0.w, p1.x, p1.y, p1.z, p1.w};
#pragma unroll
  for (int i = 0; i < 4; ++i) {
    unsigned h0 = f2bf(ff[2 * i]), h1 = f2bf(ff[2 * i + 1]);
    h[i] = h0 | (h1 << 16);
    unsigned l0 = f2bf(ff[2 * i] - bf2f(h0));
    unsigned l1 = f2bf(ff[2 * i + 1] - bf2f(h1));
    lo[i] = l0 | (l1 << 16);
  }
}

// ---------------- W split setup: fp32 W -> chunk-major, pre-swizzled bf16 hi/lo ----------------
// W2[kc][e][p][j]: 16B slot p holds logical slot sl = p ^ (e&15);
// sl<8: hi bf16 of W[e][kc*64 + sl*8 + j]; sl>=8: lo bf16 (residual) of same.
__global__ void moe_wsplit(const float* __restrict__ W, ushort* __restrict__ W2) {
  const int sid = blockIdx.x * 256 + threadIdx.x;   // 0..16383 slots
  const int p  = sid & 15;
  const int e  = (sid >> 4) & 63;
  const int kc = sid >> 10;
  const int sl = p ^ (e & 15);
  const int k0 = kc * BK + (sl & 7) * 8;
  const float* src = W + (size_t)e * DDIM + k0;
  float f[8];
  *(float4*)&f[0] = *(const float4*)src;
  *(float4*)&f[4] = *(const float4*)(src + 4);
  ushort o[8];
  if (sl < 8) {
#pragma unroll
    for (int j = 0; j < 8; ++j) o[j] = (ushort)f2bf(f[j]);
  } else {
#pragma unroll
    for (int j = 0; j < 8; ++j) {
      unsigned hb = f2bf(f[j]);
      o[j] = (ushort)f2bf(f[j] - bf2f(hb));
    }
  }
  *(short8v*)(W2 + (size_t)sid * 8) = *(const short8v*)o;
}

// ---------------- main kernel: reg-direct X, glds W, 32x32x16 bf16x2 MFMA ----------------
__global__ __launch_bounds__(256, 2) void moe_gate_main(
    const float* __restrict__ X, const ushort* __restrict__ W2,
    float* __restrict__ out, float* __restrict__ gsum, float* __restrict__ gce,
    int* __restrict__ flag_cnt, int* __restrict__ flag_tok)
{
  // GEMM phase: two 16 KiB W-tile buffers @0 / @16384.
  // Epilogue aliases with the proven round-3 layout (47104 B total).
  __shared__ __align__(16) char smem[47104];

  float* xs   = (float*)smem;            // scoresT [64][STR]
  float* wsm  = (float*)(smem + 17408);  // logits  [64][STR]
  float* red  = (float*)(smem + 34816);  // [256]
  float* gmx  = (float*)(smem + 35840);  // [64]
  float* cval = (float*)(smem + 36096);  // [64*CSTR]
  int*   cidx = (int*)  (smem + 41472);  // [64*CSTR]
  int*   hist = (int*)  (smem + 46848);  // [64]

  const int tid = threadIdx.x;
  const int tok_base = blockIdx.x * TPB;
  const int bb = blockIdx.x >> 7;        // 128 blocks per batch

  const int l = tid & 63, q = tid >> 6;
  const int wm = q >> 1, wn = q & 1;     // token half / expert half
  const int rr = l & 31;                 // A row (token) == B col (expert)
  const int kh = l >> 5;                 // k half within 16-step

  // lane's private X slice: row (wm*32+rr), k = kc*64 + s*16 + kh*8 + {0..7}
  const float* xrow = X + (size_t)(tok_base + wm * 32 + rr) * DDIM + kh * 8;
  const char* w2c = (const char*)W2;
  const int btrow = (wn * 32 + rr) * 256;      // byte row in B tile
  const int bxor  = (wn * 32 + rr) & 15;       // slot swizzle

  f32x16 acc = (f32x16)0.0f;
  float4 px[8];
  unsigned aH[16], aL[16];

  // ---- prologue: X(0) + W(0) ----
#pragma unroll
  for (int s = 0; s < 4; ++s) {
    px[2 * s]     = *(const float4*)(xrow + s * 16);
    px[2 * s + 1] = *(const float4*)(xrow + s * 16 + 4);
  }
#pragma unroll
  for (int i = 0; i < 4; ++i)
    gload_lds16(w2c + q * 4096 + i * 1024 + l * 16, smem + q * 4096 + i * 1024);
#pragma unroll
  for (int s = 0; s < 4; ++s) conv8(px[2 * s], px[2 * s + 1], &aH[4 * s], &aL[4 * s]);
  __syncthreads();

  int cur = 0;
#pragma unroll 1
  for (int kc = 0; kc < NCHK; ++kc) {
    if (kc + 1 < NCHK) {
      const float* xr = xrow + (kc + 1) * BK;
#pragma unroll
      for (int s = 0; s < 4; ++s) {
        px[2 * s]     = *(const float4*)(xr + s * 16);
        px[2 * s + 1] = *(const float4*)(xr + s * 16 + 4);
      }
      const char* g = w2c + (size_t)(kc + 1) * WTILE + q * 4096 + l * 16;
      char* d = smem + ((cur ^ 1) * 16384) + q * 4096;
#pragma unroll
      for (int i = 0; i < 4; ++i) gload_lds16(g + i * 1024, d + i * 1024);
    }
    // compute chunk kc from registers + LDS buf[cur]
    const char* tb = smem + cur * 16384 + btrow;
#pragma unroll
    for (int s = 0; s < 4; ++s) {
      short8v bh = *(const short8v*)(tb + (((2 * s + kh) ^ bxor) * 16));
      short8v bl = *(const short8v*)(tb + (((8 + 2 * s + kh) ^ bxor) * 16));
      union { short8v v; unsigned u[4]; } ua, ul;
#pragma unroll
      for (int i = 0; i < 4; ++i) { ua.u[i] = aH[4 * s + i]; ul.u[i] = aL[4 * s + i]; }
      acc = __builtin_amdgcn_mfma_f32_32x32x16_bf16(ua.v, bh, acc, 0, 0, 0);
      acc = __builtin_amdgcn_mfma_f32_32x32x16_bf16(ul.v, bh, acc, 0, 0, 0);
      acc = __builtin_amdgcn_mfma_f32_32x32x16_bf16(ua.v, bl, acc, 0, 0, 0);
    }
    if (kc + 1 < NCHK) {
#pragma unroll
      for (int s = 0; s < 4; ++s) conv8(px[2 * s], px[2 * s + 1], &aH[4 * s], &aL[4 * s]);
    }
    __syncthreads();   // drains vmcnt(0): W(kc+1) in LDS for everyone
    cur ^= 1;
  }

  // ---- C write: 32x32 C/D layout col=lane&31, row=(r&3)+8*(r>>2)+4*(lane>>5) ----
  {
    const int ccol = wn * 32 + rr;
#pragma unroll
    for (int r = 0; r < 16; ++r) {
      const int trow = wm * 32 + (r & 3) + 8 * (r >> 2) + 4 * kh;
      wsm[trow * STR + ccol] = acc[r];
    }
  }
  if (tid < 64) hist[tid] = 0;
  __syncthreads();

  // ---- epilogue (round-3 layout, unchanged) ----
  float* logits  = wsm;   // [t][STR]
  float* scoresT = xs;    // [e][STR]
  const int t = l;

  float m = -__builtin_huge_valf();
#pragma unroll
  for (int e = 0; e < 16; ++e) m = fmaxf(m, logits[t * STR + q * 16 + e]);
  red[q * 64 + t] = m;
  __syncthreads();
  float gm = fmaxf(fmaxf(red[t], red[64 + t]), fmaxf(red[128 + t], red[192 + t]));
  if (q == 0) gmx[t] = gm;
  float z = 0.0f;
#pragma unroll
  for (int e = 0; e < 16; ++e) {
    float ev = expf(logits[t * STR + q * 16 + e] - gm);
    scoresT[(q * 16 + e) * STR + t] = ev;
    z += ev;
  }
  __syncthreads();
  red[q * 64 + t] = z;
  __syncthreads();
  float Z = red[t] + red[64 + t] + red[128 + t] + red[192 + t];
  float invZ = 1.0f / Z;
#pragma unroll
  for (int e = 0; e < 16; ++e) scoresT[(q * 16 + e) * STR + t] *= invZ;
  __syncthreads();

  // aux partials: sum scores over this block's tokens, per expert
  {
    const int e = l, g = q;
    float s = 0.0f;
#pragma unroll
    for (int tt = 0; tt < 16; ++tt) s += scoresT[e * STR + g * 16 + tt];
    red[g * 64 + e] = s;
  }
  __syncthreads();
  if (tid < 64) {
    float tot = red[tid] + red[64 + tid] + red[128 + tid] + red[192 + tid];
    atomicAdd(&gsum[bb * 64 + tid], tot);
  }

  // top-9 phase 1: per half (32 experts), strict > + ascending scan == jax tie-break
  if (tid < 128) {
    const int h = tid >> 6;
    const int eb = h * 32;
#pragma unroll 1
    for (int k = 0; k < 9; ++k) {
      float mv = -1.0f; int mi = eb;
#pragma unroll 4
      for (int e = 0; e < 32; ++e) {
        float v = scoresT[(eb + e) * STR + t];
        if (v > mv) { mv = v; mi = eb + e; }
      }
      cval[t * CSTR + h * 9 + k] = mv;
      cidx[t * CSTR + h * 9 + k] = mi;
      scoresT[mi * STR + t] = -1.0f;
    }
  }
  __syncthreads();

  // merge 18 -> top-9; flag near-ties for f64 refinement
  if (tid < 64) {
    float wv[9]; int wi[8];
#pragma unroll 1
    for (int k = 0; k < 9; ++k) {
      float mv = -1.0f; int mj = 0;
#pragma unroll 3
      for (int j = 0; j < 18; ++j) {
        float v = cval[t * CSTR + j];
        if (v > mv) { mv = v; mj = j; }
      }
      wv[k] = mv;
      if (k < 8) {
        wi[k] = cidx[t * CSTR + mj];
        atomicAdd(&hist[wi[k]], 1);
      }
      cval[t * CSTR + mj] = -1.0f;
    }
    bool flag = false;
#pragma unroll
    for (int k = 0; k < 8; ++k)
      if (wv[k + 1] >= wv[k] * (1.0f - 2.0e-5f)) flag = true;
    if (flag) {
      int p = atomicAdd(flag_cnt, 1);
      flag_tok[p] = tok_base + t;
    }
    // weights from f64 exp of logits (Z cancels in renorm; eps 1e-20 negligible)
    double ed[8]; double den = 0.0;
#pragma unroll
    for (int k = 0; k < 8; ++k) {
      ed[k] = exp((double)logits[t * STR + wi[k]] - (double)gmx[t]);
      den += ed[k];
    }
    const size_t tg = (size_t)(tok_base + t);
    *(float4*)(out + tg * 8) =
        make_float4((float)wi[0], (float)wi[1], (float)wi[2], (float)wi[3]);
    *(float4*)(out + tg * 8 + 4) =
        make_float4((float)wi[4], (float)wi[5], (float)wi[6], (float)wi[7]);
    *(float4*)(out + (size_t)TOKS * 8 + tg * 8) =
        make_float4((float)(ed[0] / den), (float)(ed[1] / den),
                    (float)(ed[2] / den), (float)(ed[3] / den));
    *(float4*)(out + (size_t)TOKS * 8 + tg * 8 + 4) =
        make_float4((float)(ed[4] / den), (float)(ed[5] / den),
                    (float)(ed[6] / den), (float)(ed[7] / den));
  }
  __syncthreads();
  if (tid < 64) atomicAdd(&gce[bb * 64 + tid], (float)hist[tid]);
}

// ---------------- f64 refinement for flagged (near-tie) tokens ----------------
__global__ __launch_bounds__(256) void moe_refine(
    const float* __restrict__ X, const float* __restrict__ W,
    float* __restrict__ out, float* __restrict__ gce,
    const int* __restrict__ flag_cnt, const int* __restrict__ flag_tok)
{
  __shared__ __align__(16) float xrow[DDIM];
  __shared__ double part[4][NEXP];
  const int tid = threadIdx.x;
  const int n = *flag_cnt;
  const int e = tid & 63;
  const int c = tid >> 6;          // K-chunk of 256
#pragma unroll 1
  for (int it = blockIdx.x; it < n; it += 256) {
    const int tok = flag_tok[it];
    __syncthreads();
    *(float4*)&xrow[tid * 4] = *(const float4*)&X[(size_t)tok * DDIM + tid * 4];
    __syncthreads();
    const float* wr = W + (size_t)e * DDIM + c * 256;
    const float* xr = xrow + c * 256;
    double s0 = 0.0, s1 = 0.0, s2 = 0.0, s3 = 0.0;
#pragma unroll 4
    for (int j = 0; j < 256; j += 4) {
      s0 += (double)xr[j]     * (double)wr[j];
      s1 += (double)xr[j + 1] * (double)wr[j + 1];
      s2 += (double)xr[j + 2] * (double)wr[j + 2];
      s3 += (double)xr[j + 3] * (double)wr[j + 3];
    }
    part[c][e] = (s0 + s1) + (s2 + s3);
    __syncthreads();
    if (tid < 64) {
      double cur = (part[0][e] + part[1][e]) + (part[2][e] + part[3][e]);
      int wi[8]; double wl[8];
#pragma unroll 1
      for (int k = 0; k < 8; ++k) {
        double mv = cur; int mi = e;
#pragma unroll
        for (int off = 1; off < 64; off <<= 1) {
          double ov = __shfl_xor(mv, off);
          int    oi = __shfl_xor(mi, off);
          if (ov > mv || (ov == mv && oi < mi)) { mv = ov; mi = oi; }
        }
        wi[k] = mi; wl[k] = mv;
        if (e == mi) cur = -1.0e300;   // knock out winner in its owner lane
      }
      if (e == 0) {
        int olde[8];
#pragma unroll
        for (int k = 0; k < 8; ++k) olde[k] = (int)out[(size_t)tok * 8 + k];
        double ex[8]; double den = 0.0;
#pragma unroll
        for (int k = 0; k < 8; ++k) { ex[k] = exp(wl[k] - wl[0]); den += ex[k]; }
#pragma unroll
        for (int k = 0; k < 8; ++k) {
          out[(size_t)tok * 8 + k] = (float)wi[k];
          out[(size_t)TOKS * 8 + (size_t)tok * 8 + k] = (float)(ex[k] / den);
        }
        const int bbb = tok >> 13;
#pragma unroll 1
        for (int k = 0; k < 8; ++k) {
          bool in_new = false, in_old = false;
          for (int j = 0; j < 8; ++j) {
            if (wi[j] == olde[k]) in_new = true;
            if (olde[j] == wi[k]) in_old = true;
          }
          if (!in_new) atomicAdd(&gce[bbb * 64 + olde[k]], -1.0f);
          if (!in_old) atomicAdd(&gce[bbb * 64 + wi[k]], 1.0f);
        }
      }
    }
  }
}

// ---------------- aux loss reduction ----------------
__global__ void moe_gate_aux(const float* __restrict__ gsum,
                             const float* __restrict__ gce,
                             float* __restrict__ out)
{
  __shared__ float r[256];
  const int tid = threadIdx.x;
  r[tid] = gce[tid] * gsum[tid];
  __syncthreads();
  for (int s = 128; s > 0; s >>= 1) {
    if (tid < s) r[tid] += r[tid + s];
    __syncthreads();
  }
  if (tid == 0)
    out[(size_t)TOKS * 16] = 0.1f * r[0] / ((float)SEQ * (float)NBATCH);
}

extern "C" void kernel_launch(void* const* d_in, const int* in_sizes, int n_in,
                              void* d_out, int out_size, void* d_ws, size_t ws_size,
                              hipStream_t stream)
{
  const float* X = (const float*)d_in[0];   // [4,8192,1024] fp32
  const float* W = (const float*)d_in[1];   // [64,1024] fp32
  float* out  = (float*)d_out;              // idx[T*8] | weights[T*8] | aux
  float* gsum = (float*)d_ws;               // [4][64]
  float* gce  = gsum + NBATCH * NEXP;       // [4][64]
  int* flag_cnt = (int*)((char*)d_ws + 2048);
  int* flag_tok = (int*)((char*)d_ws + 2176);
  // W2: chunk-major pre-swizzled bf16 hi/lo, 256 KiB at +1 MiB (ws is ~0.5 GiB per fill evidence)
  ushort* W2 = (ushort*)((char*)d_ws + (1 << 20));

  hipMemsetAsync(d_ws, 0, 2176, stream);
  moe_wsplit<<<64, 256, 0, stream>>>(W, W2);
  moe_gate_main<<<TOKS / TPB, 256, 0, stream>>>(X, W2, out, gsum, gce, flag_cnt, flag_tok);
  moe_refine<<<256, 256, 0, stream>>>(X, W, out, gce, flag_cnt, flag_tok);
  moe_gate_aux<<<1, 256, 0, stream>>>(gsum, gce, out);
}

// Round 3
// 236.505 us; speedup vs baseline: 1.0196x; 1.0196x over previous
//
#include <hip/hip_runtime.h>

#define TOKS   32768
#define NEXP   64
#define DDIM   1024
#define SEQ    8192
#define NBATCH 4
#define TPB    64      // tokens per block
#define STR    68      // epilogue row stride (floats)
#define CSTR   21      // candidate row stride
#define BK     64      // K-chunk
#define NCHK   (DDIM / BK)          // 16
#define WTILE  16384                // W2 bytes per chunk: 64 e x 16 slots x 16B
#define XTILE  16384                // X tile bytes per chunk: 64 tok x 64 k x 4B

typedef __attribute__((ext_vector_type(8)))  short short8v;  // 8 bf16 (4 VGPR) MFMA operand
typedef __attribute__((ext_vector_type(16))) float f32x16;   // 32x32 accumulator

// exact RNE float->bf16 (branchless), and exact bf16->float
__device__ __forceinline__ unsigned f2bf(float x) {
  unsigned u = __float_as_uint(x);
  return (u + 0x7fffu + ((u >> 16) & 1u)) >> 16;
}
__device__ __forceinline__ float bf2f(unsigned h) { return __uint_as_float(h << 16); }

__device__ __forceinline__ void gload_lds16(const void* g, void* s) {
  __builtin_amdgcn_global_load_lds(
      (const __attribute__((address_space(1))) unsigned int*)g,
      (__attribute__((address_space(3))) unsigned int*)s, 16, 0, 0);
}

// convert 8 consecutive-k floats -> packed bf16 hi (4 u32) and lo (4 u32)
__device__ __forceinline__ void conv8(const float4 p0, const float4 p1,
                                      unsigned* h, unsigned* lo) {
  float ff[8] = {p0.x, p0.y, p0.z, p0.w, p1.x, p1.y, p1.z, p1.w};
#pragma unroll
  for (int i = 0; i < 4; ++i) {
    unsigned h0 = f2bf(ff[2 * i]), h1 = f2bf(ff[2 * i + 1]);
    h[i] = h0 | (h1 << 16);
    unsigned l0 = f2bf(ff[2 * i] - bf2f(h0));
    unsigned l1 = f2bf(ff[2 * i + 1] - bf2f(h1));
    lo[i] = l0 | (l1 << 16);
  }
}

// ---------------- W split setup: fp32 W -> chunk-major, pre-swizzled bf16 hi/lo ----------------
// W2[kc][e][p][j]: 16B slot p holds logical slot sl = p ^ (e&15);
// sl<8: hi bf16 of W[e][kc*64 + sl*8 + j]; sl>=8: lo bf16 (residual) of same.
__global__ void moe_wsplit(const float* __restrict__ W, ushort* __restrict__ W2) {
  const int sid = blockIdx.x * 256 + threadIdx.x;   // 0..16383 slots
  const int p  = sid & 15;
  const int e  = (sid >> 4) & 63;
  const int kc = sid >> 10;
  const int sl = p ^ (e & 15);
  const int k0 = kc * BK + (sl & 7) * 8;
  const float* src = W + (size_t)e * DDIM + k0;
  float f[8];
  *(float4*)&f[0] = *(const float4*)src;
  *(float4*)&f[4] = *(const float4*)(src + 4);
  ushort o[8];
  if (sl < 8) {
#pragma unroll
    for (int j = 0; j < 8; ++j) o[j] = (ushort)f2bf(f[j]);
  } else {
#pragma unroll
    for (int j = 0; j < 8; ++j) {
      unsigned hb = f2bf(f[j]);
      o[j] = (ushort)f2bf(f[j] - bf2f(hb));
    }
  }
  *(short8v*)(W2 + (size_t)sid * 8) = *(const short8v*)o;
}

// ---------------- main kernel: glds-staged X (source-swizzled) + W2, 32x32x16 bf16x2 ----------------
__global__ __launch_bounds__(256, 2) void moe_gate_main(
    const float* __restrict__ X, const ushort* __restrict__ W2,
    float* __restrict__ out, float* __restrict__ gsum, float* __restrict__ gce,
    int* __restrict__ flag_cnt, int* __restrict__ flag_tok)
{
  // GEMM phase: X dbuf @0/@16384, W dbuf @32768/@49152 (16 KiB each).
  // Epilogue aliases the first 47104 B with the proven round-3 layout.
  __shared__ __align__(16) char smem[65536];

  float* xs   = (float*)smem;            // scoresT [64][STR]
  float* wsm  = (float*)(smem + 17408);  // logits  [64][STR]
  float* red  = (float*)(smem + 34816);  // [256]
  float* gmx  = (float*)(smem + 35840);  // [64]
  float* cval = (float*)(smem + 36096);  // [64*CSTR]
  int*   cidx = (int*)  (smem + 41472);  // [64*CSTR]
  int*   hist = (int*)  (smem + 46848);  // [64]

  const int tid = threadIdx.x;
  const int tok_base = blockIdx.x * TPB;
  const int bb = blockIdx.x >> 7;        // 128 blocks per batch

  const int l = tid & 63, q = tid >> 6;
  const int wm = q >> 1, wn = q & 1;     // token half / expert half
  const int rr = l & 31;                 // A row (token) == B col (expert)
  const int kh = l >> 5;                 // k half within 16-step

  // ---- staging address precompute ----
  // X tile LDS layout: [64 rows][16 slots of 16B], linear (glds-written).
  // LDS[r][p] holds X[r][slot p ^ (r&15)] via source-address swizzle.
  const char* Xb = (const char*)X + (size_t)tok_base * DDIM * 4;
  int gofs[4];
#pragma unroll
  for (int i = 0; i < 4; ++i) {
    const int r  = 16 * q + 4 * i + (l >> 4);
    const int sl = (l & 15) ^ (r & 15);
    gofs[i] = r * 4096 + sl * 16;        // byte offset within this block's X rows
  }
  const char* w2c = (const char*)W2;

  // ---- compute-phase bases ----
  const int arow = (wm * 32 + rr) * 256;       // A-tile byte row
  const int brow = (wn * 32 + rr) * 256;       // B-tile byte row
  const int rxor = rr & 15;                    // slot swizzle (row&15 for both tiles)

  f32x16 accA = (f32x16)0.0f, accB = (f32x16)0.0f;

  // ---- prologue: stage X(0), W(0) into buf 0 ----
#pragma unroll
  for (int i = 0; i < 4; ++i)
    gload_lds16(Xb + gofs[i], smem + q * 4096 + i * 1024);
#pragma unroll
  for (int i = 0; i < 4; ++i)
    gload_lds16(w2c + q * 4096 + i * 1024 + l * 16, smem + 32768 + q * 4096 + i * 1024);
  __syncthreads();

  int cur = 0;
#pragma unroll 1
  for (int kc = 0; kc < NCHK; ++kc) {
    // prefetch chunk kc+1 into buf cur^1 (glds: no VGPR round-trip, no ds_write)
    if (kc + 1 < NCHK) {
      const char* xg = Xb + (kc + 1) * 256;
      char* xd = smem + (cur ^ 1) * XTILE + q * 4096;
#pragma unroll
      for (int i = 0; i < 4; ++i) gload_lds16(xg + gofs[i], xd + i * 1024);
      const char* wg = w2c + (size_t)(kc + 1) * WTILE + q * 4096 + l * 16;
      char* wd = smem + 32768 + (cur ^ 1) * WTILE + q * 4096;
#pragma unroll
      for (int i = 0; i < 4; ++i) gload_lds16(wg + i * 1024, wd + i * 1024);
    }
    // compute chunk kc from buf cur
    const char* ta = smem + cur * XTILE + arow;
    const char* tb = smem + 32768 + cur * WTILE + brow;
#pragma unroll
    for (int s = 0; s < 4; ++s) {
      const int q0 = 4 * s + 2 * kh;     // 16B-slot of this lane's 8 floats
      float4 f0 = *(const float4*)(ta + ((q0 ^ rxor) * 16));
      float4 f1 = *(const float4*)(ta + (((q0 + 1) ^ rxor) * 16));
      unsigned ah[4], al[4];
      conv8(f0, f1, ah, al);
      short8v bh = *(const short8v*)(tb + (((2 * s + kh) ^ rxor) * 16));
      short8v bl = *(const short8v*)(tb + (((8 + 2 * s + kh) ^ rxor) * 16));
      union { short8v v; unsigned u[4]; } ua, ul;
#pragma unroll
      for (int i = 0; i < 4; ++i) { ua.u[i] = ah[i]; ul.u[i] = al[i]; }
      accA = __builtin_amdgcn_mfma_f32_32x32x16_bf16(ua.v, bh, accA, 0, 0, 0);
      accB = __builtin_amdgcn_mfma_f32_32x32x16_bf16(ul.v, bh, accB, 0, 0, 0);
      accA = __builtin_amdgcn_mfma_f32_32x32x16_bf16(ua.v, bl, accA, 0, 0, 0);
    }
    __syncthreads();   // drains vmcnt(0): chunk kc+1 staged for everyone
    cur ^= 1;
  }

  // ---- C write: 32x32 C/D layout col=lane&31, row=(r&3)+8*(r>>2)+4*(lane>>5) ----
  {
    const int ccol = wn * 32 + rr;
#pragma unroll
    for (int r = 0; r < 16; ++r) {
      const int trow = wm * 32 + (r & 3) + 8 * (r >> 2) + 4 * kh;
      wsm[trow * STR + ccol] = accA[r] + accB[r];
    }
  }
  if (tid < 64) hist[tid] = 0;
  __syncthreads();

  // ---- epilogue (round-3 layout, unchanged) ----
  float* logits  = wsm;   // [t][STR]
  float* scoresT = xs;    // [e][STR]
  const int t = l;

  float m = -__builtin_huge_valf();
#pragma unroll
  for (int e = 0; e < 16; ++e) m = fmaxf(m, logits[t * STR + q * 16 + e]);
  red[q * 64 + t] = m;
  __syncthreads();
  float gm = fmaxf(fmaxf(red[t], red[64 + t]), fmaxf(red[128 + t], red[192 + t]));
  if (q == 0) gmx[t] = gm;
  float z = 0.0f;
#pragma unroll
  for (int e = 0; e < 16; ++e) {
    float ev = expf(logits[t * STR + q * 16 + e] - gm);
    scoresT[(q * 16 + e) * STR + t] = ev;
    z += ev;
  }
  __syncthreads();
  red[q * 64 + t] = z;
  __syncthreads();
  float Z = red[t] + red[64 + t] + red[128 + t] + red[192 + t];
  float invZ = 1.0f / Z;
#pragma unroll
  for (int e = 0; e < 16; ++e) scoresT[(q * 16 + e) * STR + t] *= invZ;
  __syncthreads();

  // aux partials: sum scores over this block's tokens, per expert
  {
    const int e = l, g = q;
    float s = 0.0f;
#pragma unroll
    for (int tt = 0; tt < 16; ++tt) s += scoresT[e * STR + g * 16 + tt];
    red[g * 64 + e] = s;
  }
  __syncthreads();
  if (tid < 64) {
    float tot = red[tid] + red[64 + tid] + red[128 + tid] + red[192 + tid];
    atomicAdd(&gsum[bb * 64 + tid], tot);
  }

  // top-9 phase 1: per half (32 experts), strict > + ascending scan == jax tie-break
  if (tid < 128) {
    const int h = tid >> 6;
    const int eb = h * 32;
#pragma unroll 1
    for (int k = 0; k < 9; ++k) {
      float mv = -1.0f; int mi = eb;
#pragma unroll 4
      for (int e = 0; e < 32; ++e) {
        float v = scoresT[(eb + e) * STR + t];
        if (v > mv) { mv = v; mi = eb + e; }
      }
      cval[t * CSTR + h * 9 + k] = mv;
      cidx[t * CSTR + h * 9 + k] = mi;
      scoresT[mi * STR + t] = -1.0f;
    }
  }
  __syncthreads();

  // merge 18 -> top-9; flag near-ties for f64 refinement
  if (tid < 64) {
    float wv[9]; int wi[8];
#pragma unroll 1
    for (int k = 0; k < 9; ++k) {
      float mv = -1.0f; int mj = 0;
#pragma unroll 3
      for (int j = 0; j < 18; ++j) {
        float v = cval[t * CSTR + j];
        if (v > mv) { mv = v; mj = j; }
      }
      wv[k] = mv;
      if (k < 8) {
        wi[k] = cidx[t * CSTR + mj];
        atomicAdd(&hist[wi[k]], 1);
      }
      cval[t * CSTR + mj] = -1.0f;
    }
    bool flag = false;
#pragma unroll
    for (int k = 0; k < 8; ++k)
      if (wv[k + 1] >= wv[k] * (1.0f - 2.0e-5f)) flag = true;
    if (flag) {
      int p = atomicAdd(flag_cnt, 1);
      flag_tok[p] = tok_base + t;
    }
    // weights from f64 exp of logits (Z cancels in renorm; eps 1e-20 negligible)
    double ed[8]; double den = 0.0;
#pragma unroll
    for (int k = 0; k < 8; ++k) {
      ed[k] = exp((double)logits[t * STR + wi[k]] - (double)gmx[t]);
      den += ed[k];
    }
    const size_t tg = (size_t)(tok_base + t);
    *(float4*)(out + tg * 8) =
        make_float4((float)wi[0], (float)wi[1], (float)wi[2], (float)wi[3]);
    *(float4*)(out + tg * 8 + 4) =
        make_float4((float)wi[4], (float)wi[5], (float)wi[6], (float)wi[7]);
    *(float4*)(out + (size_t)TOKS * 8 + tg * 8) =
        make_float4((float)(ed[0] / den), (float)(ed[1] / den),
                    (float)(ed[2] / den), (float)(ed[3] / den));
    *(float4*)(out + (size_t)TOKS * 8 + tg * 8 + 4) =
        make_float4((float)(ed[4] / den), (float)(ed[5] / den),
                    (float)(ed[6] / den), (float)(ed[7] / den));
  }
  __syncthreads();
  if (tid < 64) atomicAdd(&gce[bb * 64 + tid], (float)hist[tid]);
}

// ---------------- f64 refinement for flagged (near-tie) tokens ----------------
__global__ __launch_bounds__(256) void moe_refine(
    const float* __restrict__ X, const float* __restrict__ W,
    float* __restrict__ out, float* __restrict__ gce,
    const int* __restrict__ flag_cnt, const int* __restrict__ flag_tok)
{
  __shared__ __align__(16) float xrow[DDIM];
  __shared__ double part[4][NEXP];
  const int tid = threadIdx.x;
  const int n = *flag_cnt;
  const int e = tid & 63;
  const int c = tid >> 6;          // K-chunk of 256
#pragma unroll 1
  for (int it = blockIdx.x; it < n; it += 256) {
    const int tok = flag_tok[it];
    __syncthreads();
    *(float4*)&xrow[tid * 4] = *(const float4*)&X[(size_t)tok * DDIM + tid * 4];
    __syncthreads();
    const float* wr = W + (size_t)e * DDIM + c * 256;
    const float* xr = xrow + c * 256;
    double s0 = 0.0, s1 = 0.0, s2 = 0.0, s3 = 0.0;
#pragma unroll 4
    for (int j = 0; j < 256; j += 4) {
      s0 += (double)xr[j]     * (double)wr[j];
      s1 += (double)xr[j + 1] * (double)wr[j + 1];
      s2 += (double)xr[j + 2] * (double)wr[j + 2];
      s3 += (double)xr[j + 3] * (double)wr[j + 3];
    }
    part[c][e] = (s0 + s1) + (s2 + s3);
    __syncthreads();
    if (tid < 64) {
      double cur = (part[0][e] + part[1][e]) + (part[2][e] + part[3][e]);
      int wi[8]; double wl[8];
#pragma unroll 1
      for (int k = 0; k < 8; ++k) {
        double mv = cur; int mi = e;
#pragma unroll
        for (int off = 1; off < 64; off <<= 1) {
          double ov = __shfl_xor(mv, off);
          int    oi = __shfl_xor(mi, off);
          if (ov > mv || (ov == mv && oi < mi)) { mv = ov; mi = oi; }
        }
        wi[k] = mi; wl[k] = mv;
        if (e == mi) cur = -1.0e300;   // knock out winner in its owner lane
      }
      if (e == 0) {
        int olde[8];
#pragma unroll
        for (int k = 0; k < 8; ++k) olde[k] = (int)out[(size_t)tok * 8 + k];
        double ex[8]; double den = 0.0;
#pragma unroll
        for (int k = 0; k < 8; ++k) { ex[k] = exp(wl[k] - wl[0]); den += ex[k]; }
#pragma unroll
        for (int k = 0; k < 8; ++k) {
          out[(size_t)tok * 8 + k] = (float)wi[k];
          out[(size_t)TOKS * 8 + (size_t)tok * 8 + k] = (float)(ex[k] / den);
        }
        const int bbb = tok >> 13;
#pragma unroll 1
        for (int k = 0; k < 8; ++k) {
          bool in_new = false, in_old = false;
          for (int j = 0; j < 8; ++j) {
            if (wi[j] == olde[k]) in_new = true;
            if (olde[j] == wi[k]) in_old = true;
          }
          if (!in_new) atomicAdd(&gce[bbb * 64 + olde[k]], -1.0f);
          if (!in_old) atomicAdd(&gce[bbb * 64 + wi[k]], 1.0f);
        }
      }
    }
  }
}

// ---------------- aux loss reduction ----------------
__global__ void moe_gate_aux(const float* __restrict__ gsum,
                             const float* __restrict__ gce,
                             float* __restrict__ out)
{
  __shared__ float r[256];
  const int tid = threadIdx.x;
  r[tid] = gce[tid] * gsum[tid];
  __syncthreads();
  for (int s = 128; s > 0; s >>= 1) {
    if (tid < s) r[tid] += r[tid + s];
    __syncthreads();
  }
  if (tid == 0)
    out[(size_t)TOKS * 16] = 0.1f * r[0] / ((float)SEQ * (float)NBATCH);
}

extern "C" void kernel_launch(void* const* d_in, const int* in_sizes, int n_in,
                              void* d_out, int out_size, void* d_ws, size_t ws_size,
                              hipStream_t stream)
{
  const float* X = (const float*)d_in[0];   // [4,8192,1024] fp32
  const float* W = (const float*)d_in[1];   // [64,1024] fp32
  float* out  = (float*)d_out;              // idx[T*8] | weights[T*8] | aux
  float* gsum = (float*)d_ws;               // [4][64]
  float* gce  = gsum + NBATCH * NEXP;       // [4][64]
  int* flag_cnt = (int*)((char*)d_ws + 2048);
  int* flag_tok = (int*)((char*)d_ws + 2176);
  // W2: chunk-major pre-swizzled bf16 hi/lo, 256 KiB at +1 MiB
  ushort* W2 = (ushort*)((char*)d_ws + (1 << 20));

  hipMemsetAsync(d_ws, 0, 2176, stream);
  moe_wsplit<<<64, 256, 0, stream>>>(W, W2);
  moe_gate_main<<<TOKS / TPB, 256, 0, stream>>>(X, W2, out, gsum, gce, flag_cnt, flag_tok);
  moe_refine<<<256, 256, 0, stream>>>(X, W, out, gce, flag_cnt, flag_tok);
  moe_gate_aux<<<1, 256, 0, stream>>>(gsum, gce, out);
}